// Round 6
// baseline (7527.129 us; speedup 1.0000x reference)
//
#include <hip/hip_runtime.h>
#include <stdint.h>

#define NPOS 262144       // 512*512
#define EPS_LN 1e-5f

typedef _Float16 f16x8_t __attribute__((ext_vector_type(8)));

static __device__ __forceinline__ unsigned short f2h(float f) {
    union { _Float16 h; unsigned short u; } v;
    v.h = (_Float16)f;
    return v.u;
}
static __device__ __forceinline__ float h2f(unsigned short u) {
    union { unsigned short u; _Float16 h; } v;
    v.u = u;
    return (float)v.h;
}
static __device__ __forceinline__ float sigmoidf_(float x) {
    return 1.0f / (1.0f + expf(-x));
}

// ---------------------------------------------------------------------------
// n1: one block (128 threads) per position p.
//   LN(z[p]) in fp32  ->  a_t[h][p], b_t[h][p]  (f16, h-major)
// ---------------------------------------------------------------------------
__global__ __launch_bounds__(128)
void n1(const float* __restrict__ z, const float* __restrict__ mask,
        const float* __restrict__ lng, const float* __restrict__ lnb,
        const float* __restrict__ w_ap, const float* __restrict__ b_ap,
        const float* __restrict__ w_ag, const float* __restrict__ b_ag,
        const float* __restrict__ w_bp, const float* __restrict__ b_bp,
        const float* __restrict__ w_bg, const float* __restrict__ b_bg,
        unsigned short* __restrict__ a_t, unsigned short* __restrict__ b_t)
{
    const int p = blockIdx.x;
    const int c = threadIdx.x;          // channel 0..127
    __shared__ float zn[128];
    __shared__ float part[4];

    float v = z[(size_t)p * 128 + c];
    float s = v, s2 = v * v;
    #pragma unroll
    for (int off = 1; off < 64; off <<= 1) {
        s  += __shfl_xor(s, off);
        s2 += __shfl_xor(s2, off);
    }
    if ((c & 63) == 0) { part[(c >> 6) * 2] = s; part[(c >> 6) * 2 + 1] = s2; }
    __syncthreads();
    float ts = part[0] + part[2], ts2 = part[1] + part[3];
    float mu = ts * (1.0f / 128.0f);
    float var = ts2 * (1.0f / 128.0f) - mu * mu;
    float rstd = rsqrtf(var + EPS_LN);
    zn[c] = (v - mu) * rstd * lng[c] + lnb[c];
    __syncthreads();

    float aP = 0.f, aG = 0.f, bP = 0.f, bG = 0.f;
    for (int in = 0; in < 128; ++in) {
        float zv = zn[in];
        aP += zv * w_ap[in * 128 + c];
        aG += zv * w_ag[in * 128 + c];
        bP += zv * w_bp[in * 128 + c];
        bG += zv * w_bg[in * 128 + c];
    }
    float m = mask[p];
    float av = m * sigmoidf_(aG + b_ag[c]) * (aP + b_ap[c]);
    float bv = m * sigmoidf_(bG + b_bg[c]) * (bP + b_bp[c]);
    a_t[(size_t)c * NPOS + p] = f2h(av);
    b_t[(size_t)c * NPOS + p] = f2h(bv);
}

// ---------------------------------------------------------------------------
// n2: block (256 threads) per (i, h).  x[h][i][k] = sum_j a[h][i][j]*b[h][k][j]
// fp32 accumulate, f16 store.
// ---------------------------------------------------------------------------
__global__ __launch_bounds__(256)
void n2(const unsigned short* __restrict__ a_t,
        const unsigned short* __restrict__ b_t,
        unsigned short* __restrict__ x_t)
{
    const int i = blockIdx.x, h = blockIdx.y, t = threadIdx.x;
    __shared__ __align__(16) unsigned short arow[512];
    const unsigned short* ap = a_t + (size_t)h * NPOS + (size_t)i * 512;
    arow[t]       = ap[t];
    arow[t + 256] = ap[t + 256];
    __syncthreads();
    #pragma unroll 1
    for (int kk = 0; kk < 2; ++kk) {
        int k = kk * 256 + t;
        const unsigned short* brow = b_t + (size_t)h * NPOS + (size_t)k * 512;
        float acc = 0.f;
        for (int j8 = 0; j8 < 64; ++j8) {
            f16x8_t bv = *(const f16x8_t*)(brow + j8 * 8);
            f16x8_t av = *(const f16x8_t*)(arow + j8 * 8);
            #pragma unroll
            for (int e = 0; e < 8; ++e) acc += (float)av[e] * (float)bv[e];
        }
        x_t[(size_t)h * NPOS + (size_t)i * 512 + k] = f2h(acc);
    }
}

// ---------------------------------------------------------------------------
// n34: one block (128 threads) per position p.
//   out[p][c] = ( LN_h(x[:,p]) @ w_z + b_z ) * sigmoid( LN(z[p]) @ w_g + b_g )
// all fp32.
// ---------------------------------------------------------------------------
__global__ __launch_bounds__(128)
void n34(const unsigned short* __restrict__ x_t, const float* __restrict__ z,
         const float* __restrict__ lngo, const float* __restrict__ lnbo,
         const float* __restrict__ w_z, const float* __restrict__ b_z,
         const float* __restrict__ lngi, const float* __restrict__ lnbi,
         const float* __restrict__ w_g, const float* __restrict__ b_g,
         float* __restrict__ out)
{
    const int p = blockIdx.x;
    const int c = threadIdx.x;
    __shared__ float xo[128];
    __shared__ float zn[128];
    __shared__ float part[4];

    // LN over x's h-channels
    float xv = h2f(x_t[(size_t)c * NPOS + p]);
    float s = xv, s2 = xv * xv;
    #pragma unroll
    for (int off = 1; off < 64; off <<= 1) {
        s  += __shfl_xor(s, off);
        s2 += __shfl_xor(s2, off);
    }
    if ((c & 63) == 0) { part[(c >> 6) * 2] = s; part[(c >> 6) * 2 + 1] = s2; }
    __syncthreads();
    float ts = part[0] + part[2], ts2 = part[1] + part[3];
    float mu = ts * (1.0f / 128.0f);
    float var = ts2 * (1.0f / 128.0f) - mu * mu;
    float rstd = rsqrtf(var + EPS_LN);
    xo[c] = (xv - mu) * rstd * lngo[c] + lnbo[c];

    // LN over z's channels (gate path)
    float zv = z[(size_t)p * 128 + c];
    s = zv; s2 = zv * zv;
    #pragma unroll
    for (int off = 1; off < 64; off <<= 1) {
        s  += __shfl_xor(s, off);
        s2 += __shfl_xor(s2, off);
    }
    __syncthreads();     // everyone done reading part before rewrite
    if ((c & 63) == 0) { part[(c >> 6) * 2] = s; part[(c >> 6) * 2 + 1] = s2; }
    __syncthreads();
    ts = part[0] + part[2]; ts2 = part[1] + part[3];
    mu = ts * (1.0f / 128.0f);
    var = ts2 * (1.0f / 128.0f) - mu * mu;
    rstd = rsqrtf(var + EPS_LN);
    zn[c] = (zv - mu) * rstd * lngi[c] + lnbi[c];
    __syncthreads();

    float acc = 0.f, accg = 0.f;
    for (int in = 0; in < 128; ++in) {
        acc  += xo[in] * w_z[in * 128 + c];
        accg += zn[in] * w_g[in * 128 + c];
    }
    out[(size_t)p * 128 + c] = (acc + b_z[c]) * sigmoidf_(accg + b_g[c]);
}

extern "C" void kernel_launch(void* const* d_in, const int* in_sizes, int n_in,
                              void* d_out, int out_size, void* d_ws, size_t ws_size,
                              hipStream_t stream) {
    const float* z        = (const float*)d_in[0];
    const float* mask     = (const float*)d_in[1];
    const float* ln_in_g  = (const float*)d_in[2];
    const float* ln_in_b  = (const float*)d_in[3];
    const float* w_ap     = (const float*)d_in[4];
    const float* b_ap     = (const float*)d_in[5];
    const float* w_ag     = (const float*)d_in[6];
    const float* b_ag     = (const float*)d_in[7];
    const float* w_bp     = (const float*)d_in[8];
    const float* b_bp     = (const float*)d_in[9];
    const float* w_bg     = (const float*)d_in[10];
    const float* b_bg     = (const float*)d_in[11];
    const float* w_g      = (const float*)d_in[12];
    const float* b_g      = (const float*)d_in[13];
    const float* ln_out_g = (const float*)d_in[14];
    const float* ln_out_b = (const float*)d_in[15];
    const float* w_z      = (const float*)d_in[16];
    const float* b_z      = (const float*)d_in[17];
    float* out = (float*)d_out;

    char* ws = (char*)d_ws;
    const size_t MB64 = (size_t)NPOS * 128 * 2;   // 64 MB per f16 plane-set
    unsigned short* a_t = (unsigned short*)(ws);
    unsigned short* b_t = (unsigned short*)(ws + MB64);
    unsigned short* x_t = (unsigned short*)(ws + 2 * MB64);   // 192 MB total

    n1<<<NPOS, 128, 0, stream>>>(z, mask, ln_in_g, ln_in_b,
                                 w_ap, b_ap, w_ag, b_ag,
                                 w_bp, b_bp, w_bg, b_bg,
                                 a_t, b_t);
    n2<<<dim3(512, 128), 256, 0, stream>>>(a_t, b_t, x_t);
    n34<<<NPOS, 128, 0, stream>>>(x_t, z, ln_out_g, ln_out_b, w_z, b_z,
                                  ln_in_g, ln_in_b, w_g, b_g, out);
}

// Round 7
// 3445.768 us; speedup vs baseline: 2.1845x; 2.1845x over previous
//
#include <hip/hip_runtime.h>
#include <stdint.h>

#define NPOS 262144       // 512*512
#define EPS_LN 1e-5f

typedef _Float16 f16x8_t __attribute__((ext_vector_type(8)));
typedef float f32x4_t __attribute__((ext_vector_type(4)));

static __device__ __forceinline__ unsigned short f2h(float f) {
    union { _Float16 h; unsigned short u; } v;
    v.h = (_Float16)f;
    return v.u;
}
static __device__ __forceinline__ float h2f(unsigned short u) {
    union { unsigned short u; _Float16 h; } v;
    v.u = u;
    return (float)v.h;
}
static __device__ __forceinline__ float sigmoidf_(float x) {
    return 1.0f / (1.0f + expf(-x));
}

#define GLOAD_LDS16(gp, lp) __builtin_amdgcn_global_load_lds( \
    (const __attribute__((address_space(1))) void*)(gp), \
    (__attribute__((address_space(3))) void*)(lp), 16, 0, 0)

// ---------------------------------------------------------------------------
// n1 (KNOWN GOOD): one block (128 threads) per position p.
//   LN(z[p]) in fp32  ->  a_t[h][p], b_t[h][p]  (f16, h-major)
// ---------------------------------------------------------------------------
__global__ __launch_bounds__(128)
void n1(const float* __restrict__ z, const float* __restrict__ mask,
        const float* __restrict__ lng, const float* __restrict__ lnb,
        const float* __restrict__ w_ap, const float* __restrict__ b_ap,
        const float* __restrict__ w_ag, const float* __restrict__ b_ag,
        const float* __restrict__ w_bp, const float* __restrict__ b_bp,
        const float* __restrict__ w_bg, const float* __restrict__ b_bg,
        unsigned short* __restrict__ a_t, unsigned short* __restrict__ b_t)
{
    const int p = blockIdx.x;
    const int c = threadIdx.x;          // channel 0..127
    __shared__ float zn[128];
    __shared__ float part[4];

    float v = z[(size_t)p * 128 + c];
    float s = v, s2 = v * v;
    #pragma unroll
    for (int off = 1; off < 64; off <<= 1) {
        s  += __shfl_xor(s, off);
        s2 += __shfl_xor(s2, off);
    }
    if ((c & 63) == 0) { part[(c >> 6) * 2] = s; part[(c >> 6) * 2 + 1] = s2; }
    __syncthreads();
    float ts = part[0] + part[2], ts2 = part[1] + part[3];
    float mu = ts * (1.0f / 128.0f);
    float var = ts2 * (1.0f / 128.0f) - mu * mu;
    float rstd = rsqrtf(var + EPS_LN);
    zn[c] = (v - mu) * rstd * lng[c] + lnb[c];
    __syncthreads();

    float aP = 0.f, aG = 0.f, bP = 0.f, bG = 0.f;
    for (int in = 0; in < 128; ++in) {
        float zv = zn[in];
        aP += zv * w_ap[in * 128 + c];
        aG += zv * w_ag[in * 128 + c];
        bP += zv * w_bp[in * 128 + c];
        bG += zv * w_bg[in * 128 + c];
    }
    float m = mask[p];
    float av = m * sigmoidf_(aG + b_ag[c]) * (aP + b_ap[c]);
    float bv = m * sigmoidf_(bG + b_bg[c]) * (bP + b_bp[c]);
    a_t[(size_t)c * NPOS + p] = f2h(av);
    b_t[(size_t)c * NPOS + p] = f2h(bv);
}

// ---------------------------------------------------------------------------
// k2 (FAST, under test): per-h triangle GEMM
//   x_t[h][i][k] = sum_j a_t[h][i][j] * b_t[h][k][j]
// 128x128 tile, BK=64, global_load_lds staging (m97 structure), f16 store.
// grid: (16 tiles, 128 h), 256 threads.
// ---------------------------------------------------------------------------
__global__ __launch_bounds__(256, 2)
void k2_tri(const unsigned short* __restrict__ a_t,
            const unsigned short* __restrict__ b_t,
            unsigned short* __restrict__ x_t) {
    __shared__ char sA[16384];   // [128][64] f16 linear
    __shared__ char sB[16384];
    const int t = threadIdx.x;
    const int lane = t & 63;
    const int w = t >> 6;
    const int wr = w >> 1, wc = w & 1;
    const int h = blockIdx.y;
    const int i0 = (blockIdx.x >> 2) * 128;
    const int k0 = (blockIdx.x & 3) * 128;
    const unsigned short* Abase = a_t + (size_t)h * NPOS;
    const unsigned short* Bbase = b_t + (size_t)h * NPOS;

    f32x4_t zero = {0.f, 0.f, 0.f, 0.f};
    f32x4_t acc[4][4];
    #pragma unroll
    for (int m = 0; m < 4; ++m)
        #pragma unroll
        for (int n = 0; n < 4; ++n) acc[m][n] = zero;

    for (int kt = 0; kt < 8; ++kt) {
        #pragma unroll
        for (int pass = 0; pass < 4; ++pass) {
            int ci = pass * 256 + t;
            int row = ci >> 3, ch = ci & 7;
            const unsigned short* gA = Abase + (size_t)(i0 + row) * 512 + kt * 64 + ch * 8;
            const unsigned short* gB = Bbase + (size_t)(k0 + row) * 512 + kt * 64 + ch * 8;
            GLOAD_LDS16(gA, sA + w * 1024 + pass * 4096);
            GLOAD_LDS16(gB, sB + w * 1024 + pass * 4096);
        }
        __syncthreads();
        #pragma unroll
        for (int ks = 0; ks < 2; ++ks) {
            f16x8_t af[4], bf[4];
            #pragma unroll
            for (int m = 0; m < 4; ++m) {
                int ar = wr * 64 + m * 16 + (lane & 15);
                af[m] = *(const f16x8_t*)(sA + ar * 128 + ks * 64 + (lane >> 4) * 16);
            }
            #pragma unroll
            for (int n = 0; n < 4; ++n) {
                int br = wc * 64 + n * 16 + (lane & 15);
                bf[n] = *(const f16x8_t*)(sB + br * 128 + ks * 64 + (lane >> 4) * 16);
            }
            #pragma unroll
            for (int m = 0; m < 4; ++m)
                #pragma unroll
                for (int n = 0; n < 4; ++n)
                    acc[m][n] = __builtin_amdgcn_mfma_f32_16x16x32_f16(af[m], bf[n], acc[m][n], 0, 0, 0);
        }
        __syncthreads();
    }
    #pragma unroll
    for (int m = 0; m < 4; ++m) {
        int i = i0 + wr * 64 + m * 16 + (lane >> 4) * 4;
        #pragma unroll
        for (int n = 0; n < 4; ++n) {
            int k = k0 + wc * 64 + n * 16 + (lane & 15);
            #pragma unroll
            for (int r = 0; r < 4; ++r) {
                x_t[(size_t)h * NPOS + (size_t)(i + r) * 512 + k] = f2h(acc[m][n][r]);
            }
        }
    }
}

// ---------------------------------------------------------------------------
// n34 (KNOWN GOOD): one block (128 threads) per position p.
//   out[p][c] = ( LN_h(x[:,p]) @ w_z + b_z ) * sigmoid( LN(z[p]) @ w_g + b_g )
// ---------------------------------------------------------------------------
__global__ __launch_bounds__(128)
void n34(const unsigned short* __restrict__ x_t, const float* __restrict__ z,
         const float* __restrict__ lngo, const float* __restrict__ lnbo,
         const float* __restrict__ w_z, const float* __restrict__ b_z,
         const float* __restrict__ lngi, const float* __restrict__ lnbi,
         const float* __restrict__ w_g, const float* __restrict__ b_g,
         float* __restrict__ out)
{
    const int p = blockIdx.x;
    const int c = threadIdx.x;
    __shared__ float xo[128];
    __shared__ float zn[128];
    __shared__ float part[4];

    // LN over x's h-channels
    float xv = h2f(x_t[(size_t)c * NPOS + p]);
    float s = xv, s2 = xv * xv;
    #pragma unroll
    for (int off = 1; off < 64; off <<= 1) {
        s  += __shfl_xor(s, off);
        s2 += __shfl_xor(s2, off);
    }
    if ((c & 63) == 0) { part[(c >> 6) * 2] = s; part[(c >> 6) * 2 + 1] = s2; }
    __syncthreads();
    float ts = part[0] + part[2], ts2 = part[1] + part[3];
    float mu = ts * (1.0f / 128.0f);
    float var = ts2 * (1.0f / 128.0f) - mu * mu;
    float rstd = rsqrtf(var + EPS_LN);
    xo[c] = (xv - mu) * rstd * lngo[c] + lnbo[c];

    // LN over z's channels (gate path)
    float zv = z[(size_t)p * 128 + c];
    s = zv; s2 = zv * zv;
    #pragma unroll
    for (int off = 1; off < 64; off <<= 1) {
        s  += __shfl_xor(s, off);
        s2 += __shfl_xor(s2, off);
    }
    __syncthreads();     // everyone done reading part before rewrite
    if ((c & 63) == 0) { part[(c >> 6) * 2] = s; part[(c >> 6) * 2 + 1] = s2; }
    __syncthreads();
    ts = part[0] + part[2]; ts2 = part[1] + part[3];
    mu = ts * (1.0f / 128.0f);
    var = ts2 * (1.0f / 128.0f) - mu * mu;
    rstd = rsqrtf(var + EPS_LN);
    zn[c] = (zv - mu) * rstd * lngi[c] + lnbi[c];
    __syncthreads();

    float acc = 0.f, accg = 0.f;
    for (int in = 0; in < 128; ++in) {
        acc  += xo[in] * w_z[in * 128 + c];
        accg += zn[in] * w_g[in * 128 + c];
    }
    out[(size_t)p * 128 + c] = (acc + b_z[c]) * sigmoidf_(accg + b_g[c]);
}

extern "C" void kernel_launch(void* const* d_in, const int* in_sizes, int n_in,
                              void* d_out, int out_size, void* d_ws, size_t ws_size,
                              hipStream_t stream) {
    const float* z        = (const float*)d_in[0];
    const float* mask     = (const float*)d_in[1];
    const float* ln_in_g  = (const float*)d_in[2];
    const float* ln_in_b  = (const float*)d_in[3];
    const float* w_ap     = (const float*)d_in[4];
    const float* b_ap     = (const float*)d_in[5];
    const float* w_ag     = (const float*)d_in[6];
    const float* b_ag     = (const float*)d_in[7];
    const float* w_bp     = (const float*)d_in[8];
    const float* b_bp     = (const float*)d_in[9];
    const float* w_bg     = (const float*)d_in[10];
    const float* b_bg     = (const float*)d_in[11];
    const float* w_g      = (const float*)d_in[12];
    const float* b_g      = (const float*)d_in[13];
    const float* ln_out_g = (const float*)d_in[14];
    const float* ln_out_b = (const float*)d_in[15];
    const float* w_z      = (const float*)d_in[16];
    const float* b_z      = (const float*)d_in[17];
    float* out = (float*)d_out;

    char* ws = (char*)d_ws;
    const size_t MB64 = (size_t)NPOS * 128 * 2;   // 64 MB per f16 plane-set
    unsigned short* a_t = (unsigned short*)(ws);
    unsigned short* b_t = (unsigned short*)(ws + MB64);
    unsigned short* x_t = (unsigned short*)(ws + 2 * MB64);   // 192 MB total

    n1<<<NPOS, 128, 0, stream>>>(z, mask, ln_in_g, ln_in_b,
                                 w_ap, b_ap, w_ag, b_ag,
                                 w_bp, b_bp, w_bg, b_bg,
                                 a_t, b_t);
    k2_tri<<<dim3(16, 128), 256, 0, stream>>>(a_t, b_t, x_t);
    n34<<<NPOS, 128, 0, stream>>>(x_t, z, ln_out_g, ln_out_b, w_z, b_z,
                                  ln_in_g, ln_in_b, w_g, b_g, out);
}

// Round 8
// 1489.810 us; speedup vs baseline: 5.0524x; 2.3129x over previous
//
#include <hip/hip_runtime.h>
#include <stdint.h>

#define NPOS 262144       // 512*512
#define EPS_LN 1e-5f
#define ZSTRIDE 272       // 128 f16 + 16B pad (2-way LDS bank aliasing only)

typedef _Float16 f16x8_t __attribute__((ext_vector_type(8)));
typedef float f32x4_t __attribute__((ext_vector_type(4)));

static __device__ __forceinline__ unsigned short f2h(float f) {
    union { _Float16 h; unsigned short u; } v;
    v.h = (_Float16)f;
    return v.u;
}
static __device__ __forceinline__ float h2f(unsigned short u) {
    union { unsigned short u; _Float16 h; } v;
    v.u = u;
    return (float)v.h;
}
static __device__ __forceinline__ float sigmoidf_(float x) {
    return 1.0f / (1.0f + expf(-x));
}

#define GLOAD_LDS16(gp, lp) __builtin_amdgcn_global_load_lds( \
    (const __attribute__((address_space(1))) void*)(gp), \
    (__attribute__((address_space(3))) void*)(lp), 16, 0, 0)

// ---------------------------------------------------------------------------
// k1b (independent rewrite): fused LN(z) + a/b projections.
//   a_t[h][p] = mask[p]*sigmoid(zn.w_ag+b_ag)*(zn.w_ap+b_ap)   (f16, h-major)
//   b_t[h][p] likewise.
// 256 threads (4 waves), 64 positions per block, grid 4096.
// Weights read directly from f32 [in][out] global, transposed into LDS.
// ---------------------------------------------------------------------------
__global__ __launch_bounds__(256, 2)
void k1b(const float* __restrict__ z, const float* __restrict__ mask,
         const float* __restrict__ lng, const float* __restrict__ lnb,
         const float* __restrict__ w_ap, const float* __restrict__ b_ap,
         const float* __restrict__ w_ag, const float* __restrict__ b_ag,
         const float* __restrict__ w_bp, const float* __restrict__ b_bp,
         const float* __restrict__ w_bg, const float* __restrict__ b_bg,
         unsigned short* __restrict__ a_t, unsigned short* __restrict__ b_t)
{
    __shared__ char sZn[64 * ZSTRIDE];   // [64 pos][128 ch] f16, padded rows
    __shared__ char sWP[64 * ZSTRIDE];   // [64 out][128 in] f16, padded rows
    __shared__ char sWG[64 * ZSTRIDE];
    const int t = threadIdx.x;
    const int lane = t & 63;
    const int w = t >> 6;                // wave 0..3
    const int p0 = blockIdx.x * 64;

    // ---- LN staging: wave w handles rows w*16 .. w*16+15, lane -> ch {2l,2l+1}
    {
        const float g0 = lng[2 * lane], g1 = lng[2 * lane + 1];
        const float e0 = lnb[2 * lane], e1 = lnb[2 * lane + 1];
        for (int i = 0; i < 16; ++i) {
            int r = w * 16 + i;
            const float* zp = z + (size_t)(p0 + r) * 128 + 2 * lane;
            float v0 = zp[0], v1 = zp[1];
            float s = v0 + v1, s2 = v0 * v0 + v1 * v1;
            #pragma unroll
            for (int off = 1; off < 64; off <<= 1) {
                s  += __shfl_xor(s, off);
                s2 += __shfl_xor(s2, off);
            }
            float mu = s * (1.0f / 128.0f);
            float var = s2 * (1.0f / 128.0f) - mu * mu;
            float rstd = rsqrtf(var + EPS_LN);
            unsigned short h0 = f2h((v0 - mu) * rstd * g0 + e0);
            unsigned short h1 = f2h((v1 - mu) * rstd * g1 + e1);
            *(unsigned*)(sZn + r * ZSTRIDE + lane * 4) = h0 | ((unsigned)h1 << 16);
        }
    }
    // per-lane mask for this wave's 4-row groups
    const int pb = p0 + w * 16 + (lane >> 4) * 4;
    float mrow[4];
    #pragma unroll
    for (int r = 0; r < 4; ++r) mrow[r] = mask[pb + r];
    __syncthreads();

    for (int pair = 0; pair < 2; ++pair) {
        const float* WPg = pair ? w_bp : w_ap;
        const float* WGg = pair ? w_bg : w_ag;
        const float* biasP = pair ? b_bp : b_ap;
        const float* biasG = pair ? b_bg : b_ag;
        unsigned short* dst = pair ? b_t : a_t;
        for (int cb = 0; cb < 2; ++cb) {
            // ---- stage weights [out 64][in 128] via in-LDS transpose ----
            // thread t: kr = t>>4 (k row group), c = t&15 (4-out chunk)
            {
                int kr = t >> 4, c = t & 15;
                for (int it = 0; it < 8; ++it) {
                    int k = it * 16 + kr;
                    float4 vp = *(const float4*)(WPg + (size_t)k * 128 + cb * 64 + c * 4);
                    float4 vg = *(const float4*)(WGg + (size_t)k * 128 + cb * 64 + c * 4);
                    const float pe[4] = {vp.x, vp.y, vp.z, vp.w};
                    const float ge[4] = {vg.x, vg.y, vg.z, vg.w};
                    #pragma unroll
                    for (int e = 0; e < 4; ++e) {
                        *(unsigned short*)(sWP + (c * 4 + e) * ZSTRIDE + k * 2) = f2h(pe[e]);
                        *(unsigned short*)(sWG + (c * 4 + e) * ZSTRIDE + k * 2) = f2h(ge[e]);
                    }
                }
            }
            __syncthreads();
            // ---- MFMA: [16 pos] x [128 k] @ [64 out] per wave ----
            f32x4_t zero = {0.f, 0.f, 0.f, 0.f};
            f32x4_t accP[4], accG[4];
            #pragma unroll
            for (int nt = 0; nt < 4; ++nt) { accP[nt] = zero; accG[nt] = zero; }
            #pragma unroll
            for (int kk = 0; kk < 4; ++kk) {
                int abyte = (w * 16 + (lane & 15)) * ZSTRIDE + kk * 64 + (lane >> 4) * 16;
                f16x8_t af = *(const f16x8_t*)(sZn + abyte);
                #pragma unroll
                for (int nt = 0; nt < 4; ++nt) {
                    int bbyte = (nt * 16 + (lane & 15)) * ZSTRIDE + kk * 64 + (lane >> 4) * 16;
                    f16x8_t bP = *(const f16x8_t*)(sWP + bbyte);
                    f16x8_t bG = *(const f16x8_t*)(sWG + bbyte);
                    accP[nt] = __builtin_amdgcn_mfma_f32_16x16x32_f16(af, bP, accP[nt], 0, 0, 0);
                    accG[nt] = __builtin_amdgcn_mfma_f32_16x16x32_f16(af, bG, accG[nt], 0, 0, 0);
                }
            }
            __syncthreads();
            // ---- epilogue: combine + store h-major (uint2 = 4 consecutive p) ----
            #pragma unroll
            for (int nt = 0; nt < 4; ++nt) {
                int h = cb * 64 + nt * 16 + (lane & 15);
                float bPv = biasP[h], bGv = biasG[h];
                unsigned short pk[4];
                #pragma unroll
                for (int r = 0; r < 4; ++r) {
                    float v = mrow[r] * sigmoidf_(accG[nt][r] + bGv) * (accP[nt][r] + bPv);
                    pk[r] = f2h(v);
                }
                uint2 st;
                st.x = pk[0] | ((unsigned)pk[1] << 16);
                st.y = pk[2] | ((unsigned)pk[3] << 16);
                *(uint2*)(dst + (size_t)h * NPOS + pb) = st;
            }
        }
    }
}

// ---------------------------------------------------------------------------
// k2 (VALIDATED R7): per-h triangle GEMM
//   x_t[h][i][k] = sum_j a_t[h][i][j] * b_t[h][k][j]
// ---------------------------------------------------------------------------
__global__ __launch_bounds__(256, 2)
void k2_tri(const unsigned short* __restrict__ a_t,
            const unsigned short* __restrict__ b_t,
            unsigned short* __restrict__ x_t) {
    __shared__ char sA[16384];   // [128][64] f16 linear
    __shared__ char sB[16384];
    const int t = threadIdx.x;
    const int lane = t & 63;
    const int w = t >> 6;
    const int wr = w >> 1, wc = w & 1;
    const int h = blockIdx.y;
    const int i0 = (blockIdx.x >> 2) * 128;
    const int k0 = (blockIdx.x & 3) * 128;
    const unsigned short* Abase = a_t + (size_t)h * NPOS;
    const unsigned short* Bbase = b_t + (size_t)h * NPOS;

    f32x4_t zero = {0.f, 0.f, 0.f, 0.f};
    f32x4_t acc[4][4];
    #pragma unroll
    for (int m = 0; m < 4; ++m)
        #pragma unroll
        for (int n = 0; n < 4; ++n) acc[m][n] = zero;

    for (int kt = 0; kt < 8; ++kt) {
        #pragma unroll
        for (int pass = 0; pass < 4; ++pass) {
            int ci = pass * 256 + t;
            int row = ci >> 3, ch = ci & 7;
            const unsigned short* gA = Abase + (size_t)(i0 + row) * 512 + kt * 64 + ch * 8;
            const unsigned short* gB = Bbase + (size_t)(k0 + row) * 512 + kt * 64 + ch * 8;
            GLOAD_LDS16(gA, sA + w * 1024 + pass * 4096);
            GLOAD_LDS16(gB, sB + w * 1024 + pass * 4096);
        }
        __syncthreads();
        #pragma unroll
        for (int ks = 0; ks < 2; ++ks) {
            f16x8_t af[4], bf[4];
            #pragma unroll
            for (int m = 0; m < 4; ++m) {
                int ar = wr * 64 + m * 16 + (lane & 15);
                af[m] = *(const f16x8_t*)(sA + ar * 128 + ks * 64 + (lane >> 4) * 16);
            }
            #pragma unroll
            for (int n = 0; n < 4; ++n) {
                int br = wc * 64 + n * 16 + (lane & 15);
                bf[n] = *(const f16x8_t*)(sB + br * 128 + ks * 64 + (lane >> 4) * 16);
            }
            #pragma unroll
            for (int m = 0; m < 4; ++m)
                #pragma unroll
                for (int n = 0; n < 4; ++n)
                    acc[m][n] = __builtin_amdgcn_mfma_f32_16x16x32_f16(af[m], bf[n], acc[m][n], 0, 0, 0);
        }
        __syncthreads();
    }
    #pragma unroll
    for (int m = 0; m < 4; ++m) {
        int i = i0 + wr * 64 + m * 16 + (lane >> 4) * 4;
        #pragma unroll
        for (int n = 0; n < 4; ++n) {
            int k = k0 + wc * 64 + n * 16 + (lane & 15);
            #pragma unroll
            for (int r = 0; r < 4; ++r) {
                x_t[(size_t)h * NPOS + (size_t)(i + r) * 512 + k] = f2h(acc[m][n][r]);
            }
        }
    }
}

// ---------------------------------------------------------------------------
// n34 (VALIDATED R6): out[p][c] = (LN_h(x[:,p])@w_z+b_z) * sigmoid(LN(z[p])@w_g+b_g)
// ---------------------------------------------------------------------------
__global__ __launch_bounds__(128)
void n34(const unsigned short* __restrict__ x_t, const float* __restrict__ z,
         const float* __restrict__ lngo, const float* __restrict__ lnbo,
         const float* __restrict__ w_z, const float* __restrict__ b_z,
         const float* __restrict__ lngi, const float* __restrict__ lnbi,
         const float* __restrict__ w_g, const float* __restrict__ b_g,
         float* __restrict__ out)
{
    const int p = blockIdx.x;
    const int c = threadIdx.x;
    __shared__ float xo[128];
    __shared__ float zn[128];
    __shared__ float part[4];

    float xv = h2f(x_t[(size_t)c * NPOS + p]);
    float s = xv, s2 = xv * xv;
    #pragma unroll
    for (int off = 1; off < 64; off <<= 1) {
        s  += __shfl_xor(s, off);
        s2 += __shfl_xor(s2, off);
    }
    if ((c & 63) == 0) { part[(c >> 6) * 2] = s; part[(c >> 6) * 2 + 1] = s2; }
    __syncthreads();
    float ts = part[0] + part[2], ts2 = part[1] + part[3];
    float mu = ts * (1.0f / 128.0f);
    float var = ts2 * (1.0f / 128.0f) - mu * mu;
    float rstd = rsqrtf(var + EPS_LN);
    xo[c] = (xv - mu) * rstd * lngo[c] + lnbo[c];

    float zv = z[(size_t)p * 128 + c];
    s = zv; s2 = zv * zv;
    #pragma unroll
    for (int off = 1; off < 64; off <<= 1) {
        s  += __shfl_xor(s, off);
        s2 += __shfl_xor(s2, off);
    }
    __syncthreads();
    if ((c & 63) == 0) { part[(c >> 6) * 2] = s; part[(c >> 6) * 2 + 1] = s2; }
    __syncthreads();
    ts = part[0] + part[2]; ts2 = part[1] + part[3];
    mu = ts * (1.0f / 128.0f);
    var = ts2 * (1.0f / 128.0f) - mu * mu;
    rstd = rsqrtf(var + EPS_LN);
    zn[c] = (zv - mu) * rstd * lngi[c] + lnbi[c];
    __syncthreads();

    float acc = 0.f, accg = 0.f;
    for (int in = 0; in < 128; ++in) {
        acc  += xo[in] * w_z[in * 128 + c];
        accg += zn[in] * w_g[in * 128 + c];
    }
    out[(size_t)p * 128 + c] = (acc + b_z[c]) * sigmoidf_(accg + b_g[c]);
}

extern "C" void kernel_launch(void* const* d_in, const int* in_sizes, int n_in,
                              void* d_out, int out_size, void* d_ws, size_t ws_size,
                              hipStream_t stream) {
    const float* z        = (const float*)d_in[0];
    const float* mask     = (const float*)d_in[1];
    const float* ln_in_g  = (const float*)d_in[2];
    const float* ln_in_b  = (const float*)d_in[3];
    const float* w_ap     = (const float*)d_in[4];
    const float* b_ap     = (const float*)d_in[5];
    const float* w_ag     = (const float*)d_in[6];
    const float* b_ag     = (const float*)d_in[7];
    const float* w_bp     = (const float*)d_in[8];
    const float* b_bp     = (const float*)d_in[9];
    const float* w_bg     = (const float*)d_in[10];
    const float* b_bg     = (const float*)d_in[11];
    const float* w_g      = (const float*)d_in[12];
    const float* b_g      = (const float*)d_in[13];
    const float* ln_out_g = (const float*)d_in[14];
    const float* ln_out_b = (const float*)d_in[15];
    const float* w_z      = (const float*)d_in[16];
    const float* b_z      = (const float*)d_in[17];
    float* out = (float*)d_out;

    char* ws = (char*)d_ws;
    const size_t MB64 = (size_t)NPOS * 128 * 2;   // 64 MB per f16 plane-set
    unsigned short* a_t = (unsigned short*)(ws);
    unsigned short* b_t = (unsigned short*)(ws + MB64);
    unsigned short* x_t = (unsigned short*)(ws + 2 * MB64);   // 192 MB total

    k1b<<<4096, 256, 0, stream>>>(z, mask, ln_in_g, ln_in_b,
                                  w_ap, b_ap, w_ag, b_ag,
                                  w_bp, b_bp, w_bg, b_bg,
                                  a_t, b_t);
    k2_tri<<<dim3(16, 128), 256, 0, stream>>>(a_t, b_t, x_t);
    n34<<<NPOS, 128, 0, stream>>>(x_t, z, ln_out_g, ln_out_b, w_z, b_z,
                                  ln_in_g, ln_in_b, w_g, b_g, out);
}

// Round 10
// 474.397 us; speedup vs baseline: 15.8667x; 3.1404x over previous
//
#include <hip/hip_runtime.h>
#include <stdint.h>

#define NPOS 262144       // 512*512
#define EPS_LN 1e-5f
#define ZSTRIDE 272       // 128 f16 + 16B pad (breaks power-of-2 bank stride)

typedef _Float16 f16x8_t __attribute__((ext_vector_type(8)));
typedef float f32x4_t __attribute__((ext_vector_type(4)));

static __device__ __forceinline__ unsigned short f2h(float f) {
    union { _Float16 h; unsigned short u; } v;
    v.h = (_Float16)f;
    return v.u;
}
static __device__ __forceinline__ float h2f(unsigned short u) {
    union { unsigned short u; _Float16 h; } v;
    v.u = u;
    return (float)v.h;
}
static __device__ __forceinline__ float sigmoidf_(float x) {
    return 1.0f / (1.0f + expf(-x));
}

#define GLOAD_LDS16(gp, lp) __builtin_amdgcn_global_load_lds( \
    (const __attribute__((address_space(1))) void*)(gp), \
    (__attribute__((address_space(3))) void*)(lp), 16, 0, 0)

// ---------------------------------------------------------------------------
// k1b (VALIDATED R8 + zn plane write): fused LN(z) + a/b projections.
//   a_t[h][p], b_t[h][p] (f16 h-major); zn[p][ch] (f16 p-major, for k3b gate)
// ---------------------------------------------------------------------------
__global__ __launch_bounds__(256, 2)
void k1b(const float* __restrict__ z, const float* __restrict__ mask,
         const float* __restrict__ lng, const float* __restrict__ lnb,
         const float* __restrict__ w_ap, const float* __restrict__ b_ap,
         const float* __restrict__ w_ag, const float* __restrict__ b_ag,
         const float* __restrict__ w_bp, const float* __restrict__ b_bp,
         const float* __restrict__ w_bg, const float* __restrict__ b_bg,
         unsigned short* __restrict__ a_t, unsigned short* __restrict__ b_t,
         unsigned short* __restrict__ zn_out)
{
    __shared__ char sZn[64 * ZSTRIDE];   // [64 pos][128 ch] f16, padded rows
    __shared__ char sWP[64 * ZSTRIDE];   // [64 out][128 in] f16, padded rows
    __shared__ char sWG[64 * ZSTRIDE];
    const int t = threadIdx.x;
    const int lane = t & 63;
    const int w = t >> 6;                // wave 0..3
    const int p0 = blockIdx.x * 64;

    // ---- LN staging: wave w handles rows w*16 .. w*16+15, lane -> ch {2l,2l+1}
    {
        const float g0 = lng[2 * lane], g1 = lng[2 * lane + 1];
        const float e0 = lnb[2 * lane], e1 = lnb[2 * lane + 1];
        for (int i = 0; i < 16; ++i) {
            int r = w * 16 + i;
            const float* zp = z + (size_t)(p0 + r) * 128 + 2 * lane;
            float v0 = zp[0], v1 = zp[1];
            float s = v0 + v1, s2 = v0 * v0 + v1 * v1;
            #pragma unroll
            for (int off = 1; off < 64; off <<= 1) {
                s  += __shfl_xor(s, off);
                s2 += __shfl_xor(s2, off);
            }
            float mu = s * (1.0f / 128.0f);
            float var = s2 * (1.0f / 128.0f) - mu * mu;
            float rstd = rsqrtf(var + EPS_LN);
            unsigned short h0 = f2h((v0 - mu) * rstd * g0 + e0);
            unsigned short h1 = f2h((v1 - mu) * rstd * g1 + e1);
            unsigned pk = h0 | ((unsigned)h1 << 16);
            *(unsigned*)(sZn + r * ZSTRIDE + lane * 4) = pk;
            *(unsigned*)(zn_out + (size_t)(p0 + r) * 128 + 2 * lane) = pk;
        }
    }
    // per-lane mask for this wave's 4-row groups
    const int pb = p0 + w * 16 + (lane >> 4) * 4;
    float mrow[4];
    #pragma unroll
    for (int r = 0; r < 4; ++r) mrow[r] = mask[pb + r];
    __syncthreads();

    for (int pair = 0; pair < 2; ++pair) {
        const float* WPg = pair ? w_bp : w_ap;
        const float* WGg = pair ? w_bg : w_ag;
        const float* biasP = pair ? b_bp : b_ap;
        const float* biasG = pair ? b_bg : b_ag;
        unsigned short* dst = pair ? b_t : a_t;
        for (int cb = 0; cb < 2; ++cb) {
            // ---- stage weights [out 64][in 128] via in-LDS transpose ----
            {
                int kr = t >> 4, c = t & 15;
                for (int it = 0; it < 8; ++it) {
                    int k = it * 16 + kr;
                    float4 vp = *(const float4*)(WPg + (size_t)k * 128 + cb * 64 + c * 4);
                    float4 vg = *(const float4*)(WGg + (size_t)k * 128 + cb * 64 + c * 4);
                    const float pe[4] = {vp.x, vp.y, vp.z, vp.w};
                    const float ge[4] = {vg.x, vg.y, vg.z, vg.w};
                    #pragma unroll
                    for (int e = 0; e < 4; ++e) {
                        *(unsigned short*)(sWP + (c * 4 + e) * ZSTRIDE + k * 2) = f2h(pe[e]);
                        *(unsigned short*)(sWG + (c * 4 + e) * ZSTRIDE + k * 2) = f2h(ge[e]);
                    }
                }
            }
            __syncthreads();
            // ---- MFMA: [16 pos] x [128 k] @ [64 out] per wave ----
            f32x4_t zero = {0.f, 0.f, 0.f, 0.f};
            f32x4_t accP[4], accG[4];
            #pragma unroll
            for (int nt = 0; nt < 4; ++nt) { accP[nt] = zero; accG[nt] = zero; }
            #pragma unroll
            for (int kk = 0; kk < 4; ++kk) {
                int abyte = (w * 16 + (lane & 15)) * ZSTRIDE + kk * 64 + (lane >> 4) * 16;
                f16x8_t af = *(const f16x8_t*)(sZn + abyte);
                #pragma unroll
                for (int nt = 0; nt < 4; ++nt) {
                    int bbyte = (nt * 16 + (lane & 15)) * ZSTRIDE + kk * 64 + (lane >> 4) * 16;
                    f16x8_t bP = *(const f16x8_t*)(sWP + bbyte);
                    f16x8_t bG = *(const f16x8_t*)(sWG + bbyte);
                    accP[nt] = __builtin_amdgcn_mfma_f32_16x16x32_f16(af, bP, accP[nt], 0, 0, 0);
                    accG[nt] = __builtin_amdgcn_mfma_f32_16x16x32_f16(af, bG, accG[nt], 0, 0, 0);
                }
            }
            __syncthreads();
            // ---- epilogue ----
            #pragma unroll
            for (int nt = 0; nt < 4; ++nt) {
                int h = cb * 64 + nt * 16 + (lane & 15);
                float bPv = biasP[h], bGv = biasG[h];
                unsigned short pk[4];
                #pragma unroll
                for (int r = 0; r < 4; ++r) {
                    float v = mrow[r] * sigmoidf_(accG[nt][r] + bGv) * (accP[nt][r] + bPv);
                    pk[r] = f2h(v);
                }
                uint2 st;
                st.x = pk[0] | ((unsigned)pk[1] << 16);
                st.y = pk[2] | ((unsigned)pk[3] << 16);
                *(uint2*)(dst + (size_t)h * NPOS + pb) = st;
            }
        }
    }
}

// ---------------------------------------------------------------------------
// k2 (VALIDATED R7): per-h triangle GEMM
//   x_t[h][i][k] = sum_j a_t[h][i][j] * b_t[h][k][j]
// ---------------------------------------------------------------------------
__global__ __launch_bounds__(256, 2)
void k2_tri(const unsigned short* __restrict__ a_t,
            const unsigned short* __restrict__ b_t,
            unsigned short* __restrict__ x_t) {
    __shared__ char sA[16384];   // [128][64] f16 linear
    __shared__ char sB[16384];
    const int t = threadIdx.x;
    const int lane = t & 63;
    const int w = t >> 6;
    const int wr = w >> 1, wc = w & 1;
    const int h = blockIdx.y;
    const int i0 = (blockIdx.x >> 2) * 128;
    const int k0 = (blockIdx.x & 3) * 128;
    const unsigned short* Abase = a_t + (size_t)h * NPOS;
    const unsigned short* Bbase = b_t + (size_t)h * NPOS;

    f32x4_t zero = {0.f, 0.f, 0.f, 0.f};
    f32x4_t acc[4][4];
    #pragma unroll
    for (int m = 0; m < 4; ++m)
        #pragma unroll
        for (int n = 0; n < 4; ++n) acc[m][n] = zero;

    for (int kt = 0; kt < 8; ++kt) {
        #pragma unroll
        for (int pass = 0; pass < 4; ++pass) {
            int ci = pass * 256 + t;
            int row = ci >> 3, ch = ci & 7;
            const unsigned short* gA = Abase + (size_t)(i0 + row) * 512 + kt * 64 + ch * 8;
            const unsigned short* gB = Bbase + (size_t)(k0 + row) * 512 + kt * 64 + ch * 8;
            GLOAD_LDS16(gA, sA + w * 1024 + pass * 4096);
            GLOAD_LDS16(gB, sB + w * 1024 + pass * 4096);
        }
        __syncthreads();
        #pragma unroll
        for (int ks = 0; ks < 2; ++ks) {
            f16x8_t af[4], bf[4];
            #pragma unroll
            for (int m = 0; m < 4; ++m) {
                int ar = wr * 64 + m * 16 + (lane & 15);
                af[m] = *(const f16x8_t*)(sA + ar * 128 + ks * 64 + (lane >> 4) * 16);
            }
            #pragma unroll
            for (int n = 0; n < 4; ++n) {
                int br = wc * 64 + n * 16 + (lane & 15);
                bf[n] = *(const f16x8_t*)(sB + br * 128 + ks * 64 + (lane >> 4) * 16);
            }
            #pragma unroll
            for (int m = 0; m < 4; ++m)
                #pragma unroll
                for (int n = 0; n < 4; ++n)
                    acc[m][n] = __builtin_amdgcn_mfma_f32_16x16x32_f16(af[m], bf[n], acc[m][n], 0, 0, 0);
        }
        __syncthreads();
    }
    #pragma unroll
    for (int m = 0; m < 4; ++m) {
        int i = i0 + wr * 64 + m * 16 + (lane >> 4) * 4;
        #pragma unroll
        for (int n = 0; n < 4; ++n) {
            int k = k0 + wc * 64 + n * 16 + (lane & 15);
            #pragma unroll
            for (int r = 0; r < 4; ++r) {
                x_t[(size_t)h * NPOS + (size_t)(i + r) * 512 + k] = f2h(acc[m][n][r]);
            }
        }
    }
}

// ---------------------------------------------------------------------------
// k3b (under test): out[p][c] = (LN_h(x[:,p])@w_z+b_z)*sigmoid(zn[p]@w_g+b_g)
// 512 threads (8 waves), 128 positions/block, grid 2048.
// Wave w owns output cols w*16..w*16+15; w_z/w_g fragments in registers.
// Gate A-fragments read directly from the zn plane in global (L2-hot).
// ---------------------------------------------------------------------------
__global__ __launch_bounds__(512, 2)
void k3b(const unsigned short* __restrict__ x_t,
         const unsigned short* __restrict__ zn,
         const float* __restrict__ lngo, const float* __restrict__ lnbo,
         const float* __restrict__ w_z, const float* __restrict__ b_z,
         const float* __restrict__ w_g, const float* __restrict__ b_g,
         float* __restrict__ out)
{
    __shared__ char sX[128 * ZSTRIDE];   // [128 pos][128 h] f16, padded rows
    const int t = threadIdx.x, lane = t & 63, w = t >> 6;
    const int g = lane >> 4;             // k-subgroup 0..3
    const int c = w * 16 + (lane & 15);  // this wave's output column
    const int p0 = blockIdx.x * 128;

    // ---- weight fragments into registers (issue early; L2-resident) ----
    f16x8_t wzf[4], wgf[4];
    #pragma unroll
    for (int kk = 0; kk < 4; ++kk) {
        #pragma unroll
        for (int j = 0; j < 8; ++j) {
            int k = kk * 32 + g * 8 + j;
            wzf[kk][j] = (_Float16)w_z[(size_t)k * 128 + c];
            wgf[kk][j] = (_Float16)w_g[(size_t)k * 128 + c];
        }
    }
    const float bzv = b_z[c], bgv = b_g[c];

    // ---- stage x transposed: thread -> h = t>>2, quarter q = t&3 (32 p) ----
    {
        int h = t >> 2, q = t & 3;
        const unsigned short* xp = x_t + (size_t)h * NPOS + p0 + q * 32;
        #pragma unroll
        for (int jj = 0; jj < 4; ++jj) {
            uint4 v = *(const uint4*)(xp + jj * 8);
            unsigned wrds[4] = {v.x, v.y, v.z, v.w};
            #pragma unroll
            for (int e = 0; e < 4; ++e) {
                int p = q * 32 + jj * 8 + e * 2;
                *(unsigned short*)(sX + p * ZSTRIDE + h * 2) = (unsigned short)(wrds[e] & 0xffffu);
                *(unsigned short*)(sX + (p + 1) * ZSTRIDE + h * 2) = (unsigned short)(wrds[e] >> 16);
            }
        }
    }
    __syncthreads();
    // ---- LN over h, in place (4 threads per position) ----
    {
        int pos = t >> 2, q = t & 3;
        float xs[32];
        #pragma unroll
        for (int e = 0; e < 8; ++e) {
            uint2 vv = *(const uint2*)(sX + pos * ZSTRIDE + (q * 32 + e * 4) * 2);
            xs[e * 4 + 0] = h2f((unsigned short)(vv.x & 0xffffu));
            xs[e * 4 + 1] = h2f((unsigned short)(vv.x >> 16));
            xs[e * 4 + 2] = h2f((unsigned short)(vv.y & 0xffffu));
            xs[e * 4 + 3] = h2f((unsigned short)(vv.y >> 16));
        }
        float s = 0.f, s2 = 0.f;
        #pragma unroll
        for (int e = 0; e < 32; ++e) { s += xs[e]; s2 += xs[e] * xs[e]; }
        s  += __shfl_xor(s, 1);  s  += __shfl_xor(s, 2);
        s2 += __shfl_xor(s2, 1); s2 += __shfl_xor(s2, 2);
        float mu = s * (1.0f / 128.0f);
        float var = s2 * (1.0f / 128.0f) - mu * mu;
        float rstd = rsqrtf(var + EPS_LN);
        #pragma unroll
        for (int e = 0; e < 8; ++e) {
            int hb = q * 32 + e * 4;
            float4 gg = *(const float4*)(lngo + hb);
            float4 bb = *(const float4*)(lnbo + hb);
            unsigned short o0 = f2h((xs[e * 4 + 0] - mu) * rstd * gg.x + bb.x);
            unsigned short o1 = f2h((xs[e * 4 + 1] - mu) * rstd * gg.y + bb.y);
            unsigned short o2 = f2h((xs[e * 4 + 2] - mu) * rstd * gg.z + bb.z);
            unsigned short o3 = f2h((xs[e * 4 + 3] - mu) * rstd * gg.w + bb.w);
            uint2 st;
            st.x = o0 | ((unsigned)o1 << 16);
            st.y = o2 | ((unsigned)o3 << 16);
            *(uint2*)(sX + pos * ZSTRIDE + hb * 2) = st;
        }
    }
    __syncthreads();
    // ---- MFMA row tiles: D[pos][c] for 16 pos at a time ----
    f32x4_t zero = {0.f, 0.f, 0.f, 0.f};
    for (int rt = 0; rt < 8; ++rt) {
        f32x4_t accZ = zero, accG = zero;
        #pragma unroll
        for (int kk = 0; kk < 4; ++kk) {
            int row = rt * 16 + (lane & 15);
            f16x8_t ax = *(const f16x8_t*)(sX + row * ZSTRIDE + kk * 64 + g * 16);
            f16x8_t az = *(const f16x8_t*)(zn + (size_t)(p0 + row) * 128 + kk * 32 + g * 8);
            accZ = __builtin_amdgcn_mfma_f32_16x16x32_f16(ax, wzf[kk], accZ, 0, 0, 0);
            accG = __builtin_amdgcn_mfma_f32_16x16x32_f16(az, wgf[kk], accG, 0, 0, 0);
        }
        int prow = p0 + rt * 16 + g * 4;
        #pragma unroll
        for (int r = 0; r < 4; ++r) {
            out[(size_t)(prow + r) * 128 + c] = (accZ[r] + bzv) * sigmoidf_(accG[r] + bgv);
        }
    }
}

extern "C" void kernel_launch(void* const* d_in, const int* in_sizes, int n_in,
                              void* d_out, int out_size, void* d_ws, size_t ws_size,
                              hipStream_t stream) {
    const float* z        = (const float*)d_in[0];
    const float* mask     = (const float*)d_in[1];
    const float* ln_in_g  = (const float*)d_in[2];
    const float* ln_in_b  = (const float*)d_in[3];
    const float* w_ap     = (const float*)d_in[4];
    const float* b_ap     = (const float*)d_in[5];
    const float* w_ag     = (const float*)d_in[6];
    const float* b_ag     = (const float*)d_in[7];
    const float* w_bp     = (const float*)d_in[8];
    const float* b_bp     = (const float*)d_in[9];
    const float* w_bg     = (const float*)d_in[10];
    const float* b_bg     = (const float*)d_in[11];
    const float* w_g      = (const float*)d_in[12];
    const float* b_g      = (const float*)d_in[13];
    const float* ln_out_g = (const float*)d_in[14];
    const float* ln_out_b = (const float*)d_in[15];
    const float* w_z      = (const float*)d_in[16];
    const float* b_z      = (const float*)d_in[17];
    float* out = (float*)d_out;

    char* ws = (char*)d_ws;
    const size_t MB64 = (size_t)NPOS * 128 * 2;   // 64 MB per f16 plane-set
    unsigned short* a_t  = (unsigned short*)(ws);
    unsigned short* b_t  = (unsigned short*)(ws + MB64);
    unsigned short* x_t  = (unsigned short*)(ws + 2 * MB64);
    unsigned short* zn_p = (unsigned short*)(ws + 3 * MB64);  // 256 MB total

    k1b<<<4096, 256, 0, stream>>>(z, mask, ln_in_g, ln_in_b,
                                  w_ap, b_ap, w_ag, b_ag,
                                  w_bp, b_bp, w_bg, b_bg,
                                  a_t, b_t, zn_p);
    k2_tri<<<dim3(16, 128), 256, 0, stream>>>(a_t, b_t, x_t);
    k3b<<<2048, 512, 0, stream>>>(x_t, zn_p, ln_out_g, ln_out_b,
                                  w_z, b_z, w_g, b_g, out);
}

// Round 11
// 377.881 us; speedup vs baseline: 19.9193x; 1.2554x over previous
//
#include <hip/hip_runtime.h>
#include <stdint.h>

#define NPOS 262144       // 512*512
#define EPS_LN 1e-5f
#define ZSTRIDE 272       // 128 f16 + 16B pad (breaks power-of-2 bank stride)

typedef _Float16 f16x8_t __attribute__((ext_vector_type(8)));
typedef float f32x4_t __attribute__((ext_vector_type(4)));

static __device__ __forceinline__ unsigned short f2h(float f) {
    union { _Float16 h; unsigned short u; } v;
    v.h = (_Float16)f;
    return v.u;
}
static __device__ __forceinline__ float h2f(unsigned short u) {
    union { unsigned short u; _Float16 h; } v;
    v.u = u;
    return (float)v.h;
}
static __device__ __forceinline__ float sigmoidf_(float x) {
    return 1.0f / (1.0f + expf(-x));
}

#define GLOAD_LDS16(gp, lp) __builtin_amdgcn_global_load_lds( \
    (const __attribute__((address_space(1))) void*)(gp), \
    (__attribute__((address_space(3))) void*)(lp), 16, 0, 0)

// ---------------------------------------------------------------------------
// k1c: fused LN(z) + a/b projections, weights in registers (k3b pattern).
// 512 threads (8 waves), 128 positions/block, grid 2048.
// Wave w owns output cols h = w*16 + (lane&15) of all 4 projection matrices.
//   a_t[h][p], b_t[h][p] (f16 h-major); zn_out[p][ch] (f16 p-major)
// ---------------------------------------------------------------------------
__global__ __launch_bounds__(512, 2)
void k1c(const float* __restrict__ z, const float* __restrict__ mask,
         const float* __restrict__ lng, const float* __restrict__ lnb,
         const float* __restrict__ w_ap, const float* __restrict__ b_ap,
         const float* __restrict__ w_ag, const float* __restrict__ b_ag,
         const float* __restrict__ w_bp, const float* __restrict__ b_bp,
         const float* __restrict__ w_bg, const float* __restrict__ b_bg,
         unsigned short* __restrict__ a_t, unsigned short* __restrict__ b_t,
         unsigned short* __restrict__ zn_out)
{
    __shared__ char sZn[128 * ZSTRIDE];  // [128 pos][128 ch] f16, padded rows
    const int t = threadIdx.x;
    const int lane = t & 63;
    const int w = t >> 6;                // wave 0..7
    const int g = lane >> 4;             // k-subgroup 0..3
    const int l15 = lane & 15;
    const int h = w * 16 + l15;          // this wave's output column
    const int p0 = blockIdx.x * 128;

    // ---- weight B-fragments into registers (L2-resident after block 0) ----
    f16x8_t wapf[4], wagf[4], wbpf[4], wbgf[4];
    #pragma unroll
    for (int kk = 0; kk < 4; ++kk) {
        #pragma unroll
        for (int j = 0; j < 8; ++j) {
            int k = kk * 32 + g * 8 + j;
            wapf[kk][j] = (_Float16)w_ap[(size_t)k * 128 + h];
            wagf[kk][j] = (_Float16)w_ag[(size_t)k * 128 + h];
            wbpf[kk][j] = (_Float16)w_bp[(size_t)k * 128 + h];
            wbgf[kk][j] = (_Float16)w_bg[(size_t)k * 128 + h];
        }
    }
    const float bap = b_ap[h], bag = b_ag[h];
    const float bbp = b_bp[h], bbg = b_bg[h];

    // ---- LN staging: wave w handles rows w*16 .. w*16+15 (validated k1b code)
    {
        const float g0 = lng[2 * lane], g1 = lng[2 * lane + 1];
        const float e0 = lnb[2 * lane], e1 = lnb[2 * lane + 1];
        for (int i = 0; i < 16; ++i) {
            int r = w * 16 + i;
            const float* zp = z + (size_t)(p0 + r) * 128 + 2 * lane;
            float v0 = zp[0], v1 = zp[1];
            float s = v0 + v1, s2 = v0 * v0 + v1 * v1;
            #pragma unroll
            for (int off = 1; off < 64; off <<= 1) {
                s  += __shfl_xor(s, off);
                s2 += __shfl_xor(s2, off);
            }
            float mu = s * (1.0f / 128.0f);
            float var = s2 * (1.0f / 128.0f) - mu * mu;
            float rstd = rsqrtf(var + EPS_LN);
            unsigned short h0 = f2h((v0 - mu) * rstd * g0 + e0);
            unsigned short h1 = f2h((v1 - mu) * rstd * g1 + e1);
            unsigned pk = h0 | ((unsigned)h1 << 16);
            *(unsigned*)(sZn + r * ZSTRIDE + lane * 4) = pk;
            *(unsigned*)(zn_out + (size_t)(p0 + r) * 128 + 2 * lane) = pk;
        }
    }
    __syncthreads();

    // ---- MFMA row tiles: 16 positions at a time, all 4 projections ----
    f32x4_t zero = {0.f, 0.f, 0.f, 0.f};
    for (int rt = 0; rt < 8; ++rt) {
        f32x4_t accAP = zero, accAG = zero, accBP = zero, accBG = zero;
        #pragma unroll
        for (int kk = 0; kk < 4; ++kk) {
            f16x8_t ax = *(const f16x8_t*)(sZn + (rt * 16 + l15) * ZSTRIDE + kk * 64 + g * 16);
            accAP = __builtin_amdgcn_mfma_f32_16x16x32_f16(ax, wapf[kk], accAP, 0, 0, 0);
            accAG = __builtin_amdgcn_mfma_f32_16x16x32_f16(ax, wagf[kk], accAG, 0, 0, 0);
            accBP = __builtin_amdgcn_mfma_f32_16x16x32_f16(ax, wbpf[kk], accBP, 0, 0, 0);
            accBG = __builtin_amdgcn_mfma_f32_16x16x32_f16(ax, wbgf[kk], accBG, 0, 0, 0);
        }
        int pb = p0 + rt * 16 + g * 4;
        unsigned short pka[4], pkb[4];
        #pragma unroll
        for (int r = 0; r < 4; ++r) {
            float m = mask[pb + r];
            pka[r] = f2h(m * sigmoidf_(accAG[r] + bag) * (accAP[r] + bap));
            pkb[r] = f2h(m * sigmoidf_(accBG[r] + bbg) * (accBP[r] + bbp));
        }
        uint2 sta, stb;
        sta.x = pka[0] | ((unsigned)pka[1] << 16);
        sta.y = pka[2] | ((unsigned)pka[3] << 16);
        stb.x = pkb[0] | ((unsigned)pkb[1] << 16);
        stb.y = pkb[2] | ((unsigned)pkb[3] << 16);
        *(uint2*)(a_t + (size_t)h * NPOS + pb) = sta;
        *(uint2*)(b_t + (size_t)h * NPOS + pb) = stb;
    }
}

// ---------------------------------------------------------------------------
// k2 (VALIDATED R7): per-h triangle GEMM
//   x_t[h][i][k] = sum_j a_t[h][i][j] * b_t[h][k][j]
// ---------------------------------------------------------------------------
__global__ __launch_bounds__(256, 2)
void k2_tri(const unsigned short* __restrict__ a_t,
            const unsigned short* __restrict__ b_t,
            unsigned short* __restrict__ x_t) {
    __shared__ char sA[16384];   // [128][64] f16 linear
    __shared__ char sB[16384];
    const int t = threadIdx.x;
    const int lane = t & 63;
    const int w = t >> 6;
    const int wr = w >> 1, wc = w & 1;
    const int h = blockIdx.y;
    const int i0 = (blockIdx.x >> 2) * 128;
    const int k0 = (blockIdx.x & 3) * 128;
    const unsigned short* Abase = a_t + (size_t)h * NPOS;
    const unsigned short* Bbase = b_t + (size_t)h * NPOS;

    f32x4_t zero = {0.f, 0.f, 0.f, 0.f};
    f32x4_t acc[4][4];
    #pragma unroll
    for (int m = 0; m < 4; ++m)
        #pragma unroll
        for (int n = 0; n < 4; ++n) acc[m][n] = zero;

    for (int kt = 0; kt < 8; ++kt) {
        #pragma unroll
        for (int pass = 0; pass < 4; ++pass) {
            int ci = pass * 256 + t;
            int row = ci >> 3, ch = ci & 7;
            const unsigned short* gA = Abase + (size_t)(i0 + row) * 512 + kt * 64 + ch * 8;
            const unsigned short* gB = Bbase + (size_t)(k0 + row) * 512 + kt * 64 + ch * 8;
            GLOAD_LDS16(gA, sA + w * 1024 + pass * 4096);
            GLOAD_LDS16(gB, sB + w * 1024 + pass * 4096);
        }
        __syncthreads();
        #pragma unroll
        for (int ks = 0; ks < 2; ++ks) {
            f16x8_t af[4], bf[4];
            #pragma unroll
            for (int m = 0; m < 4; ++m) {
                int ar = wr * 64 + m * 16 + (lane & 15);
                af[m] = *(const f16x8_t*)(sA + ar * 128 + ks * 64 + (lane >> 4) * 16);
            }
            #pragma unroll
            for (int n = 0; n < 4; ++n) {
                int br = wc * 64 + n * 16 + (lane & 15);
                bf[n] = *(const f16x8_t*)(sB + br * 128 + ks * 64 + (lane >> 4) * 16);
            }
            #pragma unroll
            for (int m = 0; m < 4; ++m)
                #pragma unroll
                for (int n = 0; n < 4; ++n)
                    acc[m][n] = __builtin_amdgcn_mfma_f32_16x16x32_f16(af[m], bf[n], acc[m][n], 0, 0, 0);
        }
        __syncthreads();
    }
    #pragma unroll
    for (int m = 0; m < 4; ++m) {
        int i = i0 + wr * 64 + m * 16 + (lane >> 4) * 4;
        #pragma unroll
        for (int n = 0; n < 4; ++n) {
            int k = k0 + wc * 64 + n * 16 + (lane & 15);
            #pragma unroll
            for (int r = 0; r < 4; ++r) {
                x_t[(size_t)h * NPOS + (size_t)(i + r) * 512 + k] = f2h(acc[m][n][r]);
            }
        }
    }
}

// ---------------------------------------------------------------------------
// k3b (VALIDATED R10): out[p][c] = (LN_h(x[:,p])@w_z+b_z)*sigmoid(zn[p]@w_g+b_g)
// ---------------------------------------------------------------------------
__global__ __launch_bounds__(512, 2)
void k3b(const unsigned short* __restrict__ x_t,
         const unsigned short* __restrict__ zn,
         const float* __restrict__ lngo, const float* __restrict__ lnbo,
         const float* __restrict__ w_z, const float* __restrict__ b_z,
         const float* __restrict__ w_g, const float* __restrict__ b_g,
         float* __restrict__ out)
{
    __shared__ char sX[128 * ZSTRIDE];   // [128 pos][128 h] f16, padded rows
    const int t = threadIdx.x, lane = t & 63, w = t >> 6;
    const int g = lane >> 4;             // k-subgroup 0..3
    const int c = w * 16 + (lane & 15);  // this wave's output column
    const int p0 = blockIdx.x * 128;

    // ---- weight fragments into registers (issue early; L2-resident) ----
    f16x8_t wzf[4], wgf[4];
    #pragma unroll
    for (int kk = 0; kk < 4; ++kk) {
        #pragma unroll
        for (int j = 0; j < 8; ++j) {
            int k = kk * 32 + g * 8 + j;
            wzf[kk][j] = (_Float16)w_z[(size_t)k * 128 + c];
            wgf[kk][j] = (_Float16)w_g[(size_t)k * 128 + c];
        }
    }
    const float bzv = b_z[c], bgv = b_g[c];

    // ---- stage x transposed: thread -> h = t>>2, quarter q = t&3 (32 p) ----
    {
        int h = t >> 2, q = t & 3;
        const unsigned short* xp = x_t + (size_t)h * NPOS + p0 + q * 32;
        #pragma unroll
        for (int jj = 0; jj < 4; ++jj) {
            uint4 v = *(const uint4*)(xp + jj * 8);
            unsigned wrds[4] = {v.x, v.y, v.z, v.w};
            #pragma unroll
            for (int e = 0; e < 4; ++e) {
                int p = q * 32 + jj * 8 + e * 2;
                *(unsigned short*)(sX + p * ZSTRIDE + h * 2) = (unsigned short)(wrds[e] & 0xffffu);
                *(unsigned short*)(sX + (p + 1) * ZSTRIDE + h * 2) = (unsigned short)(wrds[e] >> 16);
            }
        }
    }
    __syncthreads();
    // ---- LN over h, in place (4 threads per position) ----
    {
        int pos = t >> 2, q = t & 3;
        float xs[32];
        #pragma unroll
        for (int e = 0; e < 8; ++e) {
            uint2 vv = *(const uint2*)(sX + pos * ZSTRIDE + (q * 32 + e * 4) * 2);
            xs[e * 4 + 0] = h2f((unsigned short)(vv.x & 0xffffu));
            xs[e * 4 + 1] = h2f((unsigned short)(vv.x >> 16));
            xs[e * 4 + 2] = h2f((unsigned short)(vv.y & 0xffffu));
            xs[e * 4 + 3] = h2f((unsigned short)(vv.y >> 16));
        }
        float s = 0.f, s2 = 0.f;
        #pragma unroll
        for (int e = 0; e < 32; ++e) { s += xs[e]; s2 += xs[e] * xs[e]; }
        s  += __shfl_xor(s, 1);  s  += __shfl_xor(s, 2);
        s2 += __shfl_xor(s2, 1); s2 += __shfl_xor(s2, 2);
        float mu = s * (1.0f / 128.0f);
        float var = s2 * (1.0f / 128.0f) - mu * mu;
        float rstd = rsqrtf(var + EPS_LN);
        #pragma unroll
        for (int e = 0; e < 8; ++e) {
            int hb = q * 32 + e * 4;
            float4 gg = *(const float4*)(lngo + hb);
            float4 bb = *(const float4*)(lnbo + hb);
            unsigned short o0 = f2h((xs[e * 4 + 0] - mu) * rstd * gg.x + bb.x);
            unsigned short o1 = f2h((xs[e * 4 + 1] - mu) * rstd * gg.y + bb.y);
            unsigned short o2 = f2h((xs[e * 4 + 2] - mu) * rstd * gg.z + bb.z);
            unsigned short o3 = f2h((xs[e * 4 + 3] - mu) * rstd * gg.w + bb.w);
            uint2 st;
            st.x = o0 | ((unsigned)o1 << 16);
            st.y = o2 | ((unsigned)o3 << 16);
            *(uint2*)(sX + pos * ZSTRIDE + hb * 2) = st;
        }
    }
    __syncthreads();
    // ---- MFMA row tiles: D[pos][c] for 16 pos at a time ----
    f32x4_t zero = {0.f, 0.f, 0.f, 0.f};
    for (int rt = 0; rt < 8; ++rt) {
        f32x4_t accZ = zero, accG = zero;
        #pragma unroll
        for (int kk = 0; kk < 4; ++kk) {
            int row = rt * 16 + (lane & 15);
            f16x8_t ax = *(const f16x8_t*)(sX + row * ZSTRIDE + kk * 64 + g * 16);
            f16x8_t az = *(const f16x8_t*)(zn + (size_t)(p0 + row) * 128 + kk * 32 + g * 8);
            accZ = __builtin_amdgcn_mfma_f32_16x16x32_f16(ax, wzf[kk], accZ, 0, 0, 0);
            accG = __builtin_amdgcn_mfma_f32_16x16x32_f16(az, wgf[kk], accG, 0, 0, 0);
        }
        int prow = p0 + rt * 16 + g * 4;
        #pragma unroll
        for (int r = 0; r < 4; ++r) {
            out[(size_t)(prow + r) * 128 + c] = (accZ[r] + bzv) * sigmoidf_(accG[r] + bgv);
        }
    }
}

extern "C" void kernel_launch(void* const* d_in, const int* in_sizes, int n_in,
                              void* d_out, int out_size, void* d_ws, size_t ws_size,
                              hipStream_t stream) {
    const float* z        = (const float*)d_in[0];
    const float* mask     = (const float*)d_in[1];
    const float* ln_in_g  = (const float*)d_in[2];
    const float* ln_in_b  = (const float*)d_in[3];
    const float* w_ap     = (const float*)d_in[4];
    const float* b_ap     = (const float*)d_in[5];
    const float* w_ag     = (const float*)d_in[6];
    const float* b_ag     = (const float*)d_in[7];
    const float* w_bp     = (const float*)d_in[8];
    const float* b_bp     = (const float*)d_in[9];
    const float* w_bg     = (const float*)d_in[10];
    const float* b_bg     = (const float*)d_in[11];
    const float* w_g      = (const float*)d_in[12];
    const float* b_g      = (const float*)d_in[13];
    const float* ln_out_g = (const float*)d_in[14];
    const float* ln_out_b = (const float*)d_in[15];
    const float* w_z      = (const float*)d_in[16];
    const float* b_z      = (const float*)d_in[17];
    float* out = (float*)d_out;

    char* ws = (char*)d_ws;
    const size_t MB64 = (size_t)NPOS * 128 * 2;   // 64 MB per f16 plane-set
    unsigned short* a_t  = (unsigned short*)(ws);
    unsigned short* b_t  = (unsigned short*)(ws + MB64);
    unsigned short* x_t  = (unsigned short*)(ws + 2 * MB64);
    unsigned short* zn_p = (unsigned short*)(ws + 3 * MB64);  // 256 MB total

    k1c<<<2048, 512, 0, stream>>>(z, mask, ln_in_g, ln_in_b,
                                  w_ap, b_ap, w_ag, b_ag,
                                  w_bp, b_bp, w_bg, b_bg,
                                  a_t, b_t, zn_p);
    k2_tri<<<dim3(16, 128), 256, 0, stream>>>(a_t, b_t, x_t);
    k3b<<<2048, 512, 0, stream>>>(x_t, zn_p, ln_out_g, ln_out_b,
                                  w_z, b_z, w_g, b_g, out);
}